// Round 1
// baseline (215.448 us; speedup 1.0000x reference)
//
#include <hip/hip_runtime.h>
#include <hip/hip_bf16.h>

typedef __bf16 bf16;
typedef bf16 bf16x8 __attribute__((ext_vector_type(8)));
typedef float f32x4 __attribute__((ext_vector_type(4)));

namespace {
constexpr int kB = 32;    // batch
constexpr int kT = 2048;  // seq len
constexpr int kD = 64;    // head dim
constexpr int QB = 128;   // q rows per block (4 waves x 32)
constexpr int KVB = 32;   // kv tile
}

// Flash-attention fwd, causal, fp32 in/out, bf16 MFMA compute.
// Per block: 4 waves, each owns 32 q-rows. KV staged in LDS (bf16, swizzled).
__global__ __launch_bounds__(256, 2)
void fa_fwd(const float* __restrict__ Qg, const float* __restrict__ Kg,
            const float* __restrict__ Vg, float* __restrict__ Og) {
  const int tid  = (int)threadIdx.x;
  const int wid  = tid >> 6;
  const int lane = tid & 63;
  const int g    = lane >> 4;   // 16-lane group 0..3
  const int c    = lane & 15;

  const int bid = (int)blockIdx.x;
  const int b   = bid & (kB - 1);
  const int qb  = (kT / QB - 1) - (bid >> 5);  // heavy blocks first
  const int q0  = qb * QB;
  const int qw  = q0 + wid * 32;               // this wave's first q row

  __shared__ bf16 lK[KVB * kD];      // [32 keys][64 d], swizzled
  __shared__ bf16 lV[kD * KVB];      // V^T: [64 d][32 keys], swizzled
  __shared__ bf16 lP[4][32 * 32];    // per-wave P tile, swizzled

  const float* Qb = Qg + (size_t)b * kT * kD;
  const float* Kb = Kg + (size_t)b * kT * kD;
  const float* Vb = Vg + (size_t)b * kT * kD;
  float*       Ob = Og + (size_t)b * kT * kD;

  // ---- Q fragments, scale 1/8 folded in (exact). A-frag: row=lane&15, k=g*8+j
  bf16x8 qa[2][2];
#pragma unroll
  for (int rt = 0; rt < 2; ++rt)
#pragma unroll
    for (int kk = 0; kk < 2; ++kk) {
      const float* s = Qb + (size_t)(qw + rt * 16 + c) * kD + kk * 32 + g * 8;
      f32x4 f0 = *(const f32x4*)(s);
      f32x4 f1 = *(const f32x4*)(s + 4);
      bf16x8 q;
#pragma unroll
      for (int j = 0; j < 4; ++j) {
        q[j]     = (bf16)(f0[j] * 0.125f);
        q[j + 4] = (bf16)(f1[j] * 0.125f);
      }
      qa[rt][kk] = q;
    }

  f32x4 acc[2][4];
  float m_s[2][4], l_s[2][4];
#pragma unroll
  for (int rt = 0; rt < 2; ++rt) {
#pragma unroll
    for (int dt = 0; dt < 4; ++dt) acc[rt][dt] = (f32x4){0.f, 0.f, 0.f, 0.f};
#pragma unroll
    for (int r = 0; r < 4; ++r) { m_s[rt][r] = -1e30f; l_s[rt][r] = 0.f; }
  }

  const int krow = tid >> 3, kch = tid & 7;          // K staging: 1 thread = 16B chunk
  const int vkey = tid & 31, vd0 = (tid >> 5) << 3;  // V staging: LDS-write friendly

  const int kv_end = q0 + QB;
  for (int kv = 0; kv < kv_end; kv += KVB) {
    // ---- stage K tile (row-major, byte-swizzle ^((row&7)<<4) via elem ^((row&7)<<3))
    {
      const float* s = Kb + (size_t)(kv + krow) * kD + kch * 8;
      f32x4 f0 = *(const f32x4*)(s);
      f32x4 f1 = *(const f32x4*)(s + 4);
      bf16x8 h;
#pragma unroll
      for (int j = 0; j < 4; ++j) { h[j] = (bf16)f0[j]; h[j + 4] = (bf16)f1[j]; }
      *(bf16x8*)(&lK[(krow * 64 + kch * 8) ^ ((krow & 7) << 3)]) = h;
    }
    // ---- stage V^T tile (64B rows, swizzle ^((d&3)<<3) elems)
    {
      const float* s = Vb + (size_t)(kv + vkey) * kD + vd0;
      f32x4 f0 = *(const f32x4*)(s);
      f32x4 f1 = *(const f32x4*)(s + 4);
#pragma unroll
      for (int j = 0; j < 8; ++j) {
        float fv = (j < 4) ? f0[j] : f1[j - 4];
        int d = vd0 + j;
        lV[(d * 32 + vkey) ^ ((d & 3) << 3)] = (bf16)fv;
      }
    }
    __syncthreads();

    if (kv < qw + 32) {  // wave-uniform: skip fully-masked tiles
      // ---- QK^T: S[2 rowtiles][2 coltiles], C-layout row=g*4+r, col=c
      f32x4 sc[2][2] = {};
#pragma unroll
      for (int ct = 0; ct < 2; ++ct) {
        int rk = ct * 16 + c;
#pragma unroll
        for (int kk = 0; kk < 2; ++kk) {
          bf16x8 kf = *(const bf16x8*)(&lK[(rk * 64 + kk * 32 + g * 8) ^ ((rk & 7) << 3)]);
#pragma unroll
          for (int rt = 0; rt < 2; ++rt)
            sc[rt][ct] = __builtin_amdgcn_mfma_f32_16x16x32_bf16(qa[rt][kk], kf, sc[rt][ct], 0, 0, 0);
        }
      }
      // ---- causal mask: only the diagonal tile needs it
      if (kv + KVB - 1 > qw) {
#pragma unroll
        for (int rt = 0; rt < 2; ++rt)
#pragma unroll
          for (int ct = 0; ct < 2; ++ct) {
            int key = kv + ct * 16 + c;
#pragma unroll
            for (int r = 0; r < 4; ++r) {
              int row = qw + rt * 16 + g * 4 + r;
              if (key > row) sc[rt][ct][r] = -1e30f;
            }
          }
      }
      // ---- V fragments (shared across rowtiles)
      bf16x8 vf[4];
#pragma unroll
      for (int dt = 0; dt < 4; ++dt) {
        int dr = dt * 16 + c;
        vf[dt] = *(const bf16x8*)(&lV[(dr * 32 + g * 8) ^ ((dr & 3) << 3)]);
      }
      // ---- online softmax + PV per rowtile
#pragma unroll
      for (int rt = 0; rt < 2; ++rt) {
#pragma unroll
        for (int r = 0; r < 4; ++r) {
          float mx = fmaxf(sc[rt][0][r], sc[rt][1][r]);
          mx = fmaxf(mx, __shfl_xor(mx, 1, 16));
          mx = fmaxf(mx, __shfl_xor(mx, 2, 16));
          mx = fmaxf(mx, __shfl_xor(mx, 4, 16));
          mx = fmaxf(mx, __shfl_xor(mx, 8, 16));
          float mn   = fmaxf(m_s[rt][r], mx);
          float corr = __expf(m_s[rt][r] - mn);
          m_s[rt][r] = mn;
          float p0 = __expf(sc[rt][0][r] - mn);
          float p1 = __expf(sc[rt][1][r] - mn);
          sc[rt][0][r] = p0;
          sc[rt][1][r] = p1;
          float ls = p0 + p1;
          ls += __shfl_xor(ls, 1, 16);
          ls += __shfl_xor(ls, 2, 16);
          ls += __shfl_xor(ls, 4, 16);
          ls += __shfl_xor(ls, 8, 16);
          l_s[rt][r] = l_s[rt][r] * corr + ls;
#pragma unroll
          for (int dt = 0; dt < 4; ++dt) acc[rt][dt][r] *= corr;
        }
        // ---- P via per-wave LDS re-layout (C-layout -> A-frag layout)
#pragma unroll
        for (int ct = 0; ct < 2; ++ct)
#pragma unroll
          for (int r = 0; r < 4; ++r) {
            int rp = rt * 16 + g * 4 + r;
            lP[wid][(rp * 32 + ct * 16 + c) ^ ((rp & 3) << 3)] = (bf16)sc[rt][ct][r];
          }
        int rp2 = rt * 16 + c;
        bf16x8 pf = *(const bf16x8*)(&lP[wid][(rp2 * 32 + g * 8) ^ ((rp2 & 3) << 3)]);
#pragma unroll
        for (int dt = 0; dt < 4; ++dt)
          acc[rt][dt] = __builtin_amdgcn_mfma_f32_16x16x32_bf16(pf, vf[dt], acc[rt][dt], 0, 0, 0);
      }
    }
    __syncthreads();
  }

  // ---- epilogue: O = acc / l
#pragma unroll
  for (int rt = 0; rt < 2; ++rt)
#pragma unroll
    for (int r = 0; r < 4; ++r) {
      float inv = 1.0f / l_s[rt][r];
      int row = qw + rt * 16 + g * 4 + r;
#pragma unroll
      for (int dt = 0; dt < 4; ++dt)
        Ob[(size_t)row * kD + dt * 16 + c] = acc[rt][dt][r] * inv;
    }
}

extern "C" void kernel_launch(void* const* d_in, const int* in_sizes, int n_in,
                              void* d_out, int out_size, void* d_ws, size_t ws_size,
                              hipStream_t stream) {
  const float* Q = (const float*)d_in[0];
  const float* K = (const float*)d_in[1];
  const float* V = (const float*)d_in[2];
  float* O = (float*)d_out;
  dim3 grid(kB * (kT / QB));  // 512 blocks, heavy q-blocks first
  fa_fwd<<<grid, 256, 0, stream>>>(Q, K, V, O);
}